// Round 10
// baseline (290.200 us; speedup 1.0000x reference)
//
#include <hip/hip_runtime.h>
#include <math.h>

#define BB 8
#define CC 64
#define OO 64
#define HH 128
#define WW 128
#define PP 9
#define HWIMG 16384           // H*W per batch
#define NTOT  131072          // B*H*W

typedef __attribute__((ext_vector_type(8))) _Float16 h8;
typedef __attribute__((ext_vector_type(2))) _Float16 h2;
typedef __attribute__((ext_vector_type(4))) float f32x4;

// ---------------------------------------------------------------------------
// Kernel 0: prep. blocks 0..143: wtf[p][o][c] f16. block 144: dwt[tap][c],
// bnA[c]=gamma*rsqrt(var+eps), bnB[c]=(dw_b-mean)*bnA+beta.
// ---------------------------------------------------------------------------
__global__ void k_prep(const float* __restrict__ w,
                       const float* __restrict__ dw_w,
                       const float* __restrict__ dw_b,
                       const float* __restrict__ gamma,
                       const float* __restrict__ beta,
                       const float* __restrict__ mean,
                       const float* __restrict__ var,
                       _Float16* __restrict__ wtf,
                       float* __restrict__ dwt,
                       float* __restrict__ bnA,
                       float* __restrict__ bnB) {
  int bid = blockIdx.x, t = threadIdx.x;
  if (bid < 144) {
    int i = bid * 256 + t;
    int c = i & 63, o = (i >> 6) & 63, p = i >> 12;
    wtf[i] = (_Float16)w[(o * 64 + c) * 9 + p];
  } else {
    if (t < 64) {
      float A = gamma[t] * rsqrtf(var[t] + 1e-5f);
      bnA[t] = A;
      bnB[t] = (dw_b[t] - mean[t]) * A + beta[t];
    }
    for (int i = t; i < 576; i += 256) {
      int tap = i % 9, c = i / 9;
      dwt[tap * 64 + c] = dw_w[c * 9 + tap];
    }
  }
}

// ---------------------------------------------------------------------------
// Kernel 1: x NCHW f32 -> xt[b][pix][c] f16 (NHWC) (verbatim, known good)
// ---------------------------------------------------------------------------
__global__ void __launch_bounds__(256, 4)
k_tr(const float* __restrict__ x, _Float16* __restrict__ xt) {
  __shared__ _Float16 lt[64][66];
  int bid = blockIdx.x;
  int vbid = (bid & 7) * 256 + (bid >> 3);    // XCD k <- batch k
  int tid = threadIdx.x;
  int wid = tid >> 6, ln = tid & 63;
  int b = vbid >> 8;
  int pix0 = (vbid & 255) * 64;
  const float* xbb = x + (size_t)b * CC * HWIMG;

  #pragma unroll
  for (int i = 0; i < 8; ++i) {
    int c0 = (wid * 8 + i) * 2;
    float v0 = xbb[(size_t)c0 * HWIMG + pix0 + ln];
    float v1 = xbb[(size_t)(c0 + 1) * HWIMG + pix0 + ln];
    h2 hv;
    hv[0] = (_Float16)v0;
    hv[1] = (_Float16)v1;
    *(h2*)&lt[ln][c0] = hv;
  }
  __syncthreads();

  int pq = tid >> 2, q = tid & 3;
  h8 o0, o1;
  #pragma unroll
  for (int j = 0; j < 4; ++j) {
    h2 v = *(h2*)&lt[pq][q * 16 + 2 * j];
    o0[2 * j] = v[0];
    o0[2 * j + 1] = v[1];
  }
  #pragma unroll
  for (int j = 0; j < 4; ++j) {
    h2 v = *(h2*)&lt[pq][q * 16 + 8 + 2 * j];
    o1[2 * j] = v[0];
    o1[2 * j + 1] = v[1];
  }
  _Float16* op = xt + ((size_t)((b << 14) + pix0 + pq)) * 64 + q * 16;
  *(h8*)op = o0;
  *(h8*)(op + 8) = o1;
}

// ---------------------------------------------------------------------------
// Kernel 2: offsets, LDS-free, channel-split. 8x16 px tile, 256 threads,
// 2 threads/px: wave lane ln handles px (wv*32 + (ln&31)), channels
// chalf*32..chalf*32+31 (chalf = ln>>5). Partner = lane^32 in SAME wave;
// 1x1-conv partial dots reduced via __shfl_xor(32). f32 math verbatim r6.
// 2x threads -> 16 waves/CU.
// ---------------------------------------------------------------------------
__global__ void __launch_bounds__(256, 4)
k_off2(const _Float16* __restrict__ xt,
       const float* __restrict__ dwt,
       const float* __restrict__ bnA,
       const float* __restrict__ bnB,
       const float* __restrict__ pw_w,
       const float* __restrict__ pw_b,
       float2* __restrict__ soff2) {
  int bid = blockIdx.x;
  int b = bid & 7, t = bid >> 3;           // XCD k <- batch k; 128 tiles/img
  int ty0 = (t >> 3) * 8, tx0 = (t & 7) * 16;
  int tid = threadIdx.x, wv = tid >> 6, ln = tid & 63;
  int px = wv * 32 + (ln & 31);
  int chalf = ln >> 5;
  int qy = px >> 4, qx = px & 15;
  int y = ty0 + qy, xw = tx0 + qx;
  const _Float16* xb = xt + (((size_t)b) << 14) * 64 + chalf * 32;

  float s[32];
  #pragma unroll
  for (int c = 0; c < 32; ++c) s[c] = 0.f;

  #pragma unroll
  for (int tap = 0; tap < 9; ++tap) {
    int dy = tap / 3 - 1, dx = tap % 3 - 1;
    int yy = y + dy, xx = xw + dx;
    bool ok = (yy >= 0) & (yy < HH) & (xx >= 0) & (xx < WW);
    int yc = min(max(yy, 0), HH - 1), xc = min(max(xx, 0), WW - 1);
    const _Float16* rp = xb + ((size_t)((yc << 7) + xc)) * 64;
    h8 v0 = *(const h8*)(rp);
    h8 v1 = *(const h8*)(rp + 8);
    h8 v2 = *(const h8*)(rp + 16);
    h8 v3 = *(const h8*)(rp + 24);
    if (!ok) {
      v0 = (h8)(_Float16)0.f;
      v1 = (h8)(_Float16)0.f;
      v2 = (h8)(_Float16)0.f;
      v3 = (h8)(_Float16)0.f;
    }
    const float* dwp = dwt + tap * 64 + chalf * 32;
    #pragma unroll
    for (int e = 0; e < 8; ++e) {
      s[e]      += dwp[e]      * (float)v0[e];
      s[8 + e]  += dwp[8 + e]  * (float)v1[e];
      s[16 + e] += dwp[16 + e] * (float)v2[e];
      s[24 + e] += dwp[24 + e] * (float)v3[e];
    }
  }

  // BN + SiLU (channels chalf*32 .. +31)
  #pragma unroll
  for (int c = 0; c < 32; ++c) {
    int cc = chalf * 32 + c;
    float v = s[c] * bnA[cc] + bnB[cc];
    s[c] = v / (1.f + __expf(-v));
  }

  // 1x1 conv: partial dot over this half's 32 channels, then cross-lane sum
  float off[2 * PP];
  #pragma unroll
  for (int k = 0; k < 2 * PP; ++k) {
    const float* pwp = pw_w + k * CC + chalf * 32;
    float a = 0.f;
    #pragma unroll
    for (int c = 0; c < 32; ++c) a += pwp[c] * s[c];
    off[k] = a + __shfl_xor(a, 32) + pw_b[k];
  }

  if (chalf == 0) {
    size_t idx = (size_t)(b << 14) + (y << 7) + xw;
    float fy = (float)y, fx = (float)xw;
    #pragma unroll
    for (int p = 0; p < PP; ++p) {
      float2 v;
      v.x = fy + off[2 * p]     + (float)(p / 3 - 1);
      v.y = fx + off[2 * p + 1] + (float)(p % 3 - 1);
      soff2[(size_t)p * NTOT + idx] = v;
    }
  }
}

// ---------------------------------------------------------------------------
// Kernel 3: gather+MFMA. 4x16 px tile, halo ±2 = 8x20 records (20.5 KB LDS).
// 2048 blocks -> 8 available/CU; __launch_bounds__(256,5) -> 5 blocks/CU
// (20 waves/CU). 4 waves, wave w = row w, 1 px/thread. 1-deep soff prefetch.
// ---------------------------------------------------------------------------
__global__ void __launch_bounds__(256, 5)
k_main(const _Float16* __restrict__ xt,
       const float2* __restrict__ soff2,
       const _Float16* __restrict__ wtf,
       const float* __restrict__ bias,
       float* __restrict__ out) {
  __shared__ __attribute__((aligned(16))) char smem[160 * 128];
  int bid = blockIdx.x;
  int b = bid & 7, t = bid >> 3;            // XCD k <- batch k; 256 tiles/img
  int ty0 = (t >> 3) * 4, tx0 = (t & 7) * 16;
  int tid = threadIdx.x, wid = tid >> 6, ln = tid & 63;
  int lm = ln & 15, lk = ln >> 4;
  const _Float16* xb = xt + (((size_t)b) << 14) * 64;

  int row = ty0 + wid;
  int pix = (row << 7) + tx0 + lm;
  size_t ng = (size_t)(b << 14) + pix;

  // ---- stage 8x20 halo records (clamped), chunk-swizzled: 1280 chunk-loads
  for (int ch = tid; ch < 1280; ch += 256) {
    int rec = ch >> 3, j = ch & 7;
    int ry = rec / 20, rx = rec - ry * 20;
    int yy = min(max(ty0 - 2 + ry, 0), HH - 1);
    int xx = min(max(tx0 - 2 + rx, 0), WW - 1);
    h8 v = *((const h8*)(xb + ((size_t)((yy << 7) + xx)) * 64) + (j ^ (rec & 7)));
    *(h8*)(smem + rec * 128 + j * 16) = v;
  }
  __syncthreads();

  f32x4 acc[4];
  #pragma unroll
  for (int mt = 0; mt < 4; ++mt) acc[mt] = (f32x4){0.f, 0.f, 0.f, 0.f};

  const _Float16* wl = wtf + lm * 64 + lk * 8;

  float2 sc = soff2[ng];          // p = 0
  #pragma unroll
  for (int p = 0; p < PP; ++p) {
    float2 sn;
    if (p < 8) sn = soff2[(size_t)(p + 1) * NTOT + ng];

    // ---- bilinear weights + halo indices (verified r6/r9 math)
    float sy = sc.x, sx = sc.y;
    float y0f = floorf(sy), x0f = floorf(sx);
    float wy1 = sy - y0f, wy0 = 1.f - wy1;
    float wx1 = sx - x0f, wx0 = 1.f - wx1;
    int y0 = (int)y0f, x0i = (int)x0f;
    bool vy0 = (y0 >= 0) & (y0 < HH);
    bool vy1 = (y0 + 1 >= 0) & (y0 + 1 < HH);
    bool vx0 = (x0i >= 0) & (x0i < WW);
    bool vx1 = (x0i + 1 >= 0) & (x0i + 1 < WW);
    float w00 = (vy0 && vx0) ? wy0 * wx0 : 0.f;
    float w01 = (vy0 && vx1) ? wy0 * wx1 : 0.f;
    float w10 = (vy1 && vx0) ? wy1 * wx0 : 0.f;
    float w11 = (vy1 && vx1) ? wy1 * wx1 : 0.f;

    int iy0 = min(max(y0 - ty0 + 2, 0), 6);    // halo rows 0..7, +1 safe
    int ix0 = min(max(x0i - tx0 + 2, 0), 18);  // halo cols 0..19, +1 safe
    int r00 = iy0 * 20 + ix0;
    const char* base_ = smem + r00 * 128;

    h8 L0 = *(const h8*)(base_ + ((lk ^ (r00 & 7)) << 4));
    h8 L1 = *(const h8*)(base_ + (((lk + 4) ^ (r00 & 7)) << 4));
    h8 L2 = *(const h8*)(base_ + 128 + ((lk ^ ((r00 + 1) & 7)) << 4));
    h8 L3 = *(const h8*)(base_ + 128 + (((lk + 4) ^ ((r00 + 1) & 7)) << 4));
    h8 L4 = *(const h8*)(base_ + 2560 + ((lk ^ ((r00 + 20) & 7)) << 4));
    h8 L5 = *(const h8*)(base_ + 2560 + (((lk + 4) ^ ((r00 + 20) & 7)) << 4));
    h8 L6 = *(const h8*)(base_ + 2688 + ((lk ^ ((r00 + 21) & 7)) << 4));
    h8 L7 = *(const h8*)(base_ + 2688 + (((lk + 4) ^ ((r00 + 21) & 7)) << 4));

    h8 w00v = (h8)(_Float16)w00;
    h8 w01v = (h8)(_Float16)w01;
    h8 w10v = (h8)(_Float16)w10;
    h8 w11v = (h8)(_Float16)w11;
    h8 bb0 = L0 * w00v + L2 * w01v + L4 * w10v + L6 * w11v;
    h8 bb1 = L1 * w00v + L3 * w01v + L5 * w10v + L7 * w11v;

    const _Float16* wp_ = wl + p * 4096;
    #pragma unroll
    for (int mt = 0; mt < 4; ++mt) {
      h8 a0 = *(const h8*)(wp_ + mt * 1024);
      h8 a1 = *(const h8*)(wp_ + mt * 1024 + 32);
      acc[mt] = __builtin_amdgcn_mfma_f32_16x16x32_f16(a0, bb0, acc[mt], 0, 0, 0);
      acc[mt] = __builtin_amdgcn_mfma_f32_16x16x32_f16(a1, bb1, acc[mt], 0, 0, 0);
    }
    sc = sn;
  }

  // ---- epilogue: C/D layout col=lane&15 (pixel), row=(lane>>4)*4+reg (m)
  #pragma unroll
  for (int mt = 0; mt < 4; ++mt) {
    #pragma unroll
    for (int r = 0; r < 4; ++r) {
      int m = mt * 16 + lk * 4 + r;
      out[((size_t)b * OO + m) * HWIMG + pix] = acc[mt][r] + bias[m];
    }
  }
}

// ---------------------------------------------------------------------------
extern "C" void kernel_launch(void* const* d_in, const int* in_sizes, int n_in,
                              void* d_out, int out_size, void* d_ws, size_t ws_size,
                              hipStream_t stream) {
  const float* x        = (const float*)d_in[0];
  const float* dw_w     = (const float*)d_in[1];
  const float* dw_b     = (const float*)d_in[2];
  const float* bn_gamma = (const float*)d_in[3];
  const float* bn_beta  = (const float*)d_in[4];
  const float* bn_mean  = (const float*)d_in[5];
  const float* bn_var   = (const float*)d_in[6];
  const float* pw_w     = (const float*)d_in[7];
  const float* pw_b     = (const float*)d_in[8];
  const float* weight   = (const float*)d_in[9];
  const float* bias     = (const float*)d_in[10];
  float* out = (float*)d_out;

  char* ws = (char*)d_ws;
  float2* soff2 = (float2*)ws;                                 // 9*NTOT*8 = 9.44 MB
  size_t o1 = (size_t)PP * NTOT * 8;
  _Float16* wtf = (_Float16*)(ws + o1);                        // 73728 B
  size_t o2 = o1 + (size_t)PP * OO * CC * 2;
  _Float16* xtb = (_Float16*)(ws + o2);                        // 16.8 MB
  size_t o3 = o2 + (size_t)NTOT * CC * 2;
  float* dwt = (float*)(ws + o3);                              // 2304 B
  float* bnA = (float*)(ws + o3 + 2304);
  float* bnB = (float*)(ws + o3 + 2304 + 256);

  k_prep<<<145, 256, 0, stream>>>(weight, dw_w, dw_b, bn_gamma, bn_beta,
                                  bn_mean, bn_var, wtf, dwt, bnA, bnB);
  k_tr<<<NTOT / 64, 256, 0, stream>>>(x, xtb);
  k_off2<<<NTOT / 128, 256, 0, stream>>>(xtb, dwt, bnA, bnB, pw_w, pw_b, soff2);
  k_main<<<NTOT / 64, 256, 0, stream>>>(xtb, soff2, wtf, bias, out);
}

// Round 11
// 93.283 us; speedup vs baseline: 3.1110x; 3.1110x over previous
//
#include <hip/hip_runtime.h>
#include <math.h>

#define BB 8
#define CC 64
#define OO 64
#define HH 128
#define WW 128
#define PP 9
#define HWIMG 16384           // H*W per batch
#define NTOT  131072          // B*H*W

typedef __attribute__((ext_vector_type(8))) _Float16 h8;
typedef __attribute__((ext_vector_type(2))) _Float16 h2;
typedef __attribute__((ext_vector_type(4))) float f32x4;

// ---------------------------------------------------------------------------
// Kernel 0: prep (r6 verbatim). blocks 0..143: wtf[p][o][c] f16. block 144:
// dwt[tap][c], bnA[c]=gamma*rsqrt(var+eps), bnB[c]=(dw_b-mean)*bnA+beta.
// ---------------------------------------------------------------------------
__global__ void k_prep(const float* __restrict__ w,
                       const float* __restrict__ dw_w,
                       const float* __restrict__ dw_b,
                       const float* __restrict__ gamma,
                       const float* __restrict__ beta,
                       const float* __restrict__ mean,
                       const float* __restrict__ var,
                       _Float16* __restrict__ wtf,
                       float* __restrict__ dwt,
                       float* __restrict__ bnA,
                       float* __restrict__ bnB) {
  int bid = blockIdx.x, t = threadIdx.x;
  if (bid < 144) {
    int i = bid * 256 + t;
    int c = i & 63, o = (i >> 6) & 63, p = i >> 12;
    wtf[i] = (_Float16)w[(o * 64 + c) * 9 + p];
  } else {
    if (t < 64) {
      float A = gamma[t] * rsqrtf(var[t] + 1e-5f);
      bnA[t] = A;
      bnB[t] = (dw_b[t] - mean[t]) * A + beta[t];
    }
    for (int i = t; i < 576; i += 256) {
      int tap = i % 9, c = i / 9;
      dwt[tap * 64 + c] = dw_w[c * 9 + tap];
    }
  }
}

// ---------------------------------------------------------------------------
// Kernel 1: x NCHW f32 -> xt[b][pix][c] f16 (NHWC) (r6 verbatim)
// ---------------------------------------------------------------------------
__global__ void __launch_bounds__(256, 4)
k_tr(const float* __restrict__ x, _Float16* __restrict__ xt) {
  __shared__ _Float16 lt[64][66];
  int bid = blockIdx.x;
  int vbid = (bid & 7) * 256 + (bid >> 3);    // XCD k <- batch k
  int tid = threadIdx.x;
  int wid = tid >> 6, ln = tid & 63;
  int b = vbid >> 8;
  int pix0 = (vbid & 255) * 64;
  const float* xbb = x + (size_t)b * CC * HWIMG;

  #pragma unroll
  for (int i = 0; i < 8; ++i) {
    int c0 = (wid * 8 + i) * 2;
    float v0 = xbb[(size_t)c0 * HWIMG + pix0 + ln];
    float v1 = xbb[(size_t)(c0 + 1) * HWIMG + pix0 + ln];
    h2 hv;
    hv[0] = (_Float16)v0;
    hv[1] = (_Float16)v1;
    *(h2*)&lt[ln][c0] = hv;
  }
  __syncthreads();

  int pq = tid >> 2, q = tid & 3;
  h8 o0, o1;
  #pragma unroll
  for (int j = 0; j < 4; ++j) {
    h2 v = *(h2*)&lt[pq][q * 16 + 2 * j];
    o0[2 * j] = v[0];
    o0[2 * j + 1] = v[1];
  }
  #pragma unroll
  for (int j = 0; j < 4; ++j) {
    h2 v = *(h2*)&lt[pq][q * 16 + 8 + 2 * j];
    o1[2 * j] = v[0];
    o1[2 * j + 1] = v[1];
  }
  _Float16* op = xt + ((size_t)((b << 14) + pix0 + pq)) * 64 + q * 16;
  *(h8*)op = o0;
  *(h8*)(op + 8) = o1;
}

// ---------------------------------------------------------------------------
// Kernel 2: offsets — r6 LDS-tile structure + f32 math, now 512 threads with
// intra-wave channel-split: wave lane ln -> px (wv*32 + (ln&31)), channel
// half chalf = ln>>5; 1x1 partials reduced via __shfl_xor(·,32).
// 16 waves/CU (was 8). Same plane-format soff stores.
// ---------------------------------------------------------------------------
__global__ void __launch_bounds__(512, 2)
k_off2(const _Float16* __restrict__ xt,
       const float* __restrict__ dwt,
       const float* __restrict__ bnA,
       const float* __restrict__ bnB,
       const float* __restrict__ pw_w,
       const float* __restrict__ pw_b,
       float* __restrict__ soff) {
  __shared__ __attribute__((aligned(16))) char lsm[324 * 128];
  int bid = blockIdx.x;
  int b = bid & 7, t = bid >> 3;           // XCD k <- batch k
  int ty0 = (t >> 3) * 16, tx0 = (t & 7) * 16;
  int tid = threadIdx.x;
  const _Float16* xb = xt + (((size_t)b) << 14) * 64;

  // ---- stage 18x18 halo records (zero-padded), chunk-swizzled (r6 verbatim)
  for (int ch = tid; ch < 2592; ch += 512) {
    int rec = ch >> 3, j = ch & 7;
    int ry = rec / 18, rx = rec - ry * 18;
    int yy = ty0 - 1 + ry, xx = tx0 - 1 + rx;
    bool in = (yy >= 0) & (yy < HH) & (xx >= 0) & (xx < WW);
    h8 v = (h8)(_Float16)0.f;
    if (in) v = *((const h8*)(xb + ((size_t)((yy << 7) + xx)) * 64) + (j ^ (rec & 7)));
    *(h8*)(lsm + rec * 128 + j * 16) = v;
  }
  __syncthreads();

  int wv = tid >> 6, ln = tid & 63;
  int px = wv * 32 + (ln & 31);        // 8 waves x 32 px = 256 px
  int chalf = ln >> 5;                 // 0: ch 0..31, 1: ch 32..63
  int qy = px >> 4, qx = px & 15;

  float s[32];
  #pragma unroll
  for (int c = 0; c < 32; ++c) s[c] = 0.f;

  #pragma unroll
  for (int tap = 0; tap < 9; ++tap) {
    int dy = tap / 3 - 1, dx = tap % 3 - 1;
    int rec = (qy + dy + 1) * 18 + (qx + dx + 1);
    const float* dwp = dwt + tap * 64 + chalf * 32;
    #pragma unroll
    for (int gq = 0; gq < 4; ++gq) {
      int g = chalf * 4 + gq;
      h8 v = *(const h8*)(lsm + rec * 128 + ((g ^ (rec & 7)) << 4));
      #pragma unroll
      for (int e = 0; e < 8; ++e)
        s[gq * 8 + e] += dwp[gq * 8 + e] * (float)v[e];
    }
  }

  // BN + SiLU (this half's channels)
  #pragma unroll
  for (int c = 0; c < 32; ++c) {
    int cc = chalf * 32 + c;
    float v = s[c] * bnA[cc] + bnB[cc];
    s[c] = v / (1.f + __expf(-v));
  }

  // 1x1 conv: half-dot + cross-half reduce (partner lane = ln^32, same wave)
  float off[2 * PP];
  #pragma unroll
  for (int k = 0; k < 2 * PP; ++k) {
    const float* pwp = pw_w + k * CC + chalf * 32;
    float a = 0.f;
    #pragma unroll
    for (int c = 0; c < 32; ++c) a += pwp[c] * s[c];
    off[k] = a + __shfl_xor(a, 32) + pw_b[k];
  }

  if (chalf == 0) {
    int y = ty0 + qy, xw = tx0 + qx;
    size_t idx = (size_t)(b << 14) + (y << 7) + xw;
    float fy = (float)y, fx = (float)xw;
    #pragma unroll
    for (int p = 0; p < PP; ++p) {
      soff[(size_t)(2 * p) * NTOT + idx]     = fy + off[2 * p]     + (float)(p / 3 - 1);
      soff[(size_t)(2 * p + 1) * NTOT + idx] = fx + off[2 * p + 1] + (float)(p % 3 - 1);
    }
  }
}

// ---------------------------------------------------------------------------
// Kernel 3: gather+MFMA (r6 verbatim, 47 µs known-good). 8x16 px tile,
// halo ±2 = 12x20 records in LDS. 4 waves; wave w owns rows {2w, 2w+1}.
// All soff preloaded to registers. Branch-free clamped halo reads.
// ---------------------------------------------------------------------------
__global__ void __launch_bounds__(256, 4)
k_main(const _Float16* __restrict__ xt,
       const float* __restrict__ soff,
       const _Float16* __restrict__ wtf,
       const float* __restrict__ bias,
       float* __restrict__ out) {
  __shared__ __attribute__((aligned(16))) char smem[240 * 128];
  int bid = blockIdx.x;
  int b = bid & 7, t = bid >> 3;            // XCD k <- batch k; 128 tiles/img
  int ty0 = (t >> 3) * 8, tx0 = (t & 7) * 16;
  int tid = threadIdx.x, wid = tid >> 6, ln = tid & 63;
  int lm = ln & 15, lk = ln >> 4;
  const _Float16* xb = xt + (((size_t)b) << 14) * 64;

  // ---- preload ALL soff for this thread's 2 pixels (issued before staging)
  int y0r = ty0 + wid * 2;
  int ng0 = (b << 14) + (y0r << 7) + tx0 + lm;
  float syr[PP][2], sxr[PP][2];
  #pragma unroll
  for (int p = 0; p < PP; ++p) {
    syr[p][0] = soff[(size_t)(2 * p) * NTOT + ng0];
    syr[p][1] = soff[(size_t)(2 * p) * NTOT + ng0 + 128];
    sxr[p][0] = soff[(size_t)(2 * p + 1) * NTOT + ng0];
    sxr[p][1] = soff[(size_t)(2 * p + 1) * NTOT + ng0 + 128];
  }

  // ---- stage 12x20 halo records (row/col-clamped), chunk-swizzled
  for (int ch = tid; ch < 1920; ch += 256) {
    int rec = ch >> 3, j = ch & 7;
    int ry = rec / 20, rx = rec - ry * 20;
    int yy = min(max(ty0 - 2 + ry, 0), HH - 1);
    int xx = min(max(tx0 - 2 + rx, 0), WW - 1);
    h8 v = *((const h8*)(xb + ((size_t)((yy << 7) + xx)) * 64) + (j ^ (rec & 7)));
    *(h8*)(smem + rec * 128 + j * 16) = v;
  }
  __syncthreads();

  f32x4 acc[4][2];     // [mt][nt]
  #pragma unroll
  for (int mt = 0; mt < 4; ++mt)
    #pragma unroll
    for (int nt = 0; nt < 2; ++nt) acc[mt][nt] = (f32x4){0.f, 0.f, 0.f, 0.f};

  const _Float16* wl = wtf + lm * 64 + lk * 8;   // + p*4096 + mt*1024 + kc*32

  #pragma unroll
  for (int p = 0; p < PP; ++p) {
    h8 bfr[2][2];
    #pragma unroll
    for (int nt = 0; nt < 2; ++nt) {
      float sy = syr[p][nt], sx = sxr[p][nt];
      float y0f = floorf(sy), x0f = floorf(sx);
      float wy1 = sy - y0f, wy0 = 1.f - wy1;
      float wx1 = sx - x0f, wx0 = 1.f - wx1;
      int y0 = (int)y0f, x0i = (int)x0f;
      bool vy0 = (y0 >= 0) & (y0 < HH);
      bool vy1 = (y0 + 1 >= 0) & (y0 + 1 < HH);
      bool vx0 = (x0i >= 0) & (x0i < WW);
      bool vx1 = (x0i + 1 >= 0) & (x0i + 1 < WW);
      float w00 = (vy0 && vx0) ? wy0 * wx0 : 0.f;
      float w01 = (vy0 && vx1) ? wy0 * wx1 : 0.f;
      float w10 = (vy1 && vx0) ? wy1 * wx0 : 0.f;
      float w11 = (vy1 && vx1) ? wy1 * wx1 : 0.f;

      int iy0 = min(max(y0 - ty0 + 2, 0), 11);
      int iy1 = min(max(y0 + 1 - ty0 + 2, 0), 11);
      int ix0 = min(max(x0i - tx0 + 2, 0), 19);
      int ix1 = min(max(x0i + 1 - tx0 + 2, 0), 19);
      int r00 = iy0 * 20 + ix0, r01 = iy0 * 20 + ix1;
      int r10 = iy1 * 20 + ix0, r11 = iy1 * 20 + ix1;

      h8 v00a = *(const h8*)(smem + r00 * 128 + (((lk    ) ^ (r00 & 7)) << 4));
      h8 v00b = *(const h8*)(smem + r00 * 128 + (((lk + 4) ^ (r00 & 7)) << 4));
      h8 v01a = *(const h8*)(smem + r01 * 128 + (((lk    ) ^ (r01 & 7)) << 4));
      h8 v01b = *(const h8*)(smem + r01 * 128 + (((lk + 4) ^ (r01 & 7)) << 4));
      h8 v10a = *(const h8*)(smem + r10 * 128 + (((lk    ) ^ (r10 & 7)) << 4));
      h8 v10b = *(const h8*)(smem + r10 * 128 + (((lk + 4) ^ (r10 & 7)) << 4));
      h8 v11a = *(const h8*)(smem + r11 * 128 + (((lk    ) ^ (r11 & 7)) << 4));
      h8 v11b = *(const h8*)(smem + r11 * 128 + (((lk + 4) ^ (r11 & 7)) << 4));

      h8 w00v = (h8)(_Float16)w00;
      h8 w01v = (h8)(_Float16)w01;
      h8 w10v = (h8)(_Float16)w10;
      h8 w11v = (h8)(_Float16)w11;
      bfr[nt][0] = v00a * w00v + v01a * w01v + v10a * w10v + v11a * w11v;
      bfr[nt][1] = v00b * w00v + v01b * w01v + v10b * w10v + v11b * w11v;
    }

    #pragma unroll
    for (int mt = 0; mt < 4; ++mt) {
      h8 a0 = *(const h8*)(wl + p * 4096 + mt * 1024);
      h8 a1 = *(const h8*)(wl + p * 4096 + mt * 1024 + 32);
      #pragma unroll
      for (int nt = 0; nt < 2; ++nt) {
        acc[mt][nt] = __builtin_amdgcn_mfma_f32_16x16x32_f16(a0, bfr[nt][0], acc[mt][nt], 0, 0, 0);
        acc[mt][nt] = __builtin_amdgcn_mfma_f32_16x16x32_f16(a1, bfr[nt][1], acc[mt][nt], 0, 0, 0);
      }
    }
  }

  // ---- epilogue: C/D layout col=lane&15 (pixel), row=(lane>>4)*4+reg (m)
  #pragma unroll
  for (int nt = 0; nt < 2; ++nt) {
    int pix = ((y0r + nt) << 7) + tx0 + lm;
    #pragma unroll
    for (int mt = 0; mt < 4; ++mt) {
      #pragma unroll
      for (int r = 0; r < 4; ++r) {
        int m = mt * 16 + lk * 4 + r;
        out[((size_t)b * OO + m) * HWIMG + pix] = acc[mt][nt][r] + bias[m];
      }
    }
  }
}

// ---------------------------------------------------------------------------
extern "C" void kernel_launch(void* const* d_in, const int* in_sizes, int n_in,
                              void* d_out, int out_size, void* d_ws, size_t ws_size,
                              hipStream_t stream) {
  const float* x        = (const float*)d_in[0];
  const float* dw_w     = (const float*)d_in[1];
  const float* dw_b     = (const float*)d_in[2];
  const float* bn_gamma = (const float*)d_in[3];
  const float* bn_beta  = (const float*)d_in[4];
  const float* bn_mean  = (const float*)d_in[5];
  const float* bn_var   = (const float*)d_in[6];
  const float* pw_w     = (const float*)d_in[7];
  const float* pw_b     = (const float*)d_in[8];
  const float* weight   = (const float*)d_in[9];
  const float* bias     = (const float*)d_in[10];
  float* out = (float*)d_out;

  char* ws = (char*)d_ws;
  float* soff   = (float*)ws;                                  // 18*NTOT f32 = 9.44 MB
  size_t o1 = (size_t)2 * PP * NTOT * 4;
  _Float16* wtf = (_Float16*)(ws + o1);                        // 73728 B
  size_t o2 = o1 + (size_t)PP * OO * CC * 2;
  _Float16* xtb = (_Float16*)(ws + o2);                        // 16.8 MB
  size_t o3 = o2 + (size_t)NTOT * CC * 2;
  float* dwt = (float*)(ws + o3);                              // 2304 B
  float* bnA = (float*)(ws + o3 + 2304);
  float* bnB = (float*)(ws + o3 + 2304 + 256);

  k_prep<<<145, 256, 0, stream>>>(weight, dw_w, dw_b, bn_gamma, bn_beta,
                                  bn_mean, bn_var, wtf, dwt, bnA, bnB);
  k_tr<<<NTOT / 64, 256, 0, stream>>>(x, xtb);
  k_off2<<<NTOT / 256, 512, 0, stream>>>(xtb, dwt, bnA, bnB, pw_w, pw_b, soff);
  k_main<<<NTOT / 128, 256, 0, stream>>>(xtb, soff, wtf, bias, out);
}